// Round 2
// baseline (468.801 us; speedup 1.0000x reference)
//
#include <hip/hip_runtime.h>

// Problem constants (from reference)
#define N_NODES 12500
#define N_EDGES 200000
#define DIM 32          // IN == OUT == ATTN == 32
#define N_REL 200
#define N_BASES 50
#define E_PER_BLOCK 8

// d_ws layout: [0, REL_W_BYTES): float rel_w[N_REL*DIM*DIM]  (0.8 MB)
#define REL_W_ELEMS (N_REL * DIM * DIM)
#define OUT_ELEMS   (N_NODES * DIM)

// Kernel 1: rel_w[r,i,o] = sum_b w_comp[r,b] * weight[b,i,o]
__global__ __launch_bounds__(256) void relw_kernel(
    const float* __restrict__ weight,   // [NB, IN, OUT] = [50,32,32]
    const float* __restrict__ w_comp,   // [R, NB] = [200,50]
    float* __restrict__ rel_w)          // [R, 1024]
{
    __shared__ float wc[N_BASES];
    int r = blockIdx.x;
    int tid = threadIdx.x;
    if (tid < N_BASES) wc[tid] = w_comp[r * N_BASES + tid];
    __syncthreads();
    for (int t = 0; t < 4; t++) {
        int idx = tid + t * 256;          // [0,1024)
        float sum = 0.f;
        #pragma unroll 10
        for (int b = 0; b < N_BASES; b++)
            sum = fmaf(wc[b], weight[b * 1024 + idx], sum);
        rel_w[r * 1024 + idx] = sum;
    }
}

// Kernel 2: per-edge transform + attention gate + scatter-add into fp32 out.
// 32 lanes per edge (lane j = output dim), 8 edges per 256-thread block.
__global__ __launch_bounds__(256) void edge_kernel(
    const float* __restrict__ node_feat,  // [N,32]
    const float* __restrict__ ttr,        // total_target_relation [E,32]
    const float* __restrict__ tre,        // total_relation_embed  [E,32]
    const float* __restrict__ slw,        // self_loop_weight [32,32]
    const float* __restrict__ Aw,         // [32,128]
    const float* __restrict__ Ab,         // [32]
    const float* __restrict__ Bw,         // [1,32]
    const float* __restrict__ Bb,         // [1]
    const int*  __restrict__ edge0,       // sources [E]
    const int*  __restrict__ edge1,       // targets [E]
    const int*  __restrict__ rel,         // [E]
    const float* __restrict__ rel_w,      // [R,1024] fp32
    float* __restrict__ out)              // [N,32] fp32 (pre-zeroed)
{
    // sA[k*32+j] = Aw[j,k]  (transposed: lanes differ in j -> conflict-free;
    // all lanes read same k -> consecutive banks)
    __shared__ float sA[128 * 32];   // 16 KB
    __shared__ float sS[32 * 32];    // 4 KB, sS[i*32+j] = slw[i,j]
    __shared__ float sAb[32];
    __shared__ float sBw[32];

    int tid = threadIdx.x;
    for (int x = tid; x < 128 * 32; x += 256) {
        int jj = x >> 7;      // row of Aw
        int kk = x & 127;     // col of Aw
        sA[kk * 32 + jj] = Aw[x];
    }
    for (int x = tid; x < 1024; x += 256) sS[x] = slw[x];
    if (tid < 32) { sAb[tid] = Ab[tid]; sBw[tid] = Bw[tid]; }
    __syncthreads();

    float Bb0 = Bb[0];

    int eid = blockIdx.x * E_PER_BLOCK + (tid >> 5);
    int j = tid & 31;
    if (eid >= N_EDGES) return;

    // clamp indices: if an assumption about index layout is wrong, produce
    // finite wrong values (diagnosable) instead of NaN from OOB reads
    int s = edge0[eid]; s = s < 0 ? 0 : (s >= N_NODES ? N_NODES - 1 : s);
    int t = edge1[eid]; t = t < 0 ? 0 : (t >= N_NODES ? N_NODES - 1 : t);
    int r = rel[eid];   r = r < 0 ? 0 : (r >= N_REL   ? N_REL   - 1 : r);

    float srcj = node_feat[s * DIM + j];
    float tgtj = node_feat[t * DIM + j];
    float rej  = tre[eid * DIM + j];
    float trj  = ttr[eid * DIM + j];

    const float* __restrict__ rw = rel_w + r * 1024;

    float msg = 0.f, cur = 0.f;
    float h = sAb[j];
    #pragma unroll 8
    for (int i = 0; i < 32; i++) {
        float si = __shfl(srcj, i, 32);
        float ti = __shfl(tgtj, i, 32);
        float ri = __shfl(rej,  i, 32);
        float qi = __shfl(trj,  i, 32);
        msg = fmaf(si, rw[i * 32 + j], msg);
        cur = fmaf(ti, sS[i * 32 + j], cur);
        h = fmaf(sA[( 0 + i) * 32 + j], si, h);
        h = fmaf(sA[(32 + i) * 32 + j], ti, h);
        h = fmaf(sA[(64 + i) * 32 + j], ri, h);
        h = fmaf(sA[(96 + i) * 32 + j], qi, h);
    }
    h = fmaxf(h, 0.f);                 // relu
    float p = h * sBw[j];
    // reduce over the 32-lane group
    #pragma unroll
    for (int m = 16; m > 0; m >>= 1) p += __shfl_xor(p, m, 32);
    float a = 1.f / (1.f + __expf(-(p + Bb0)));   // sigmoid

    float val = cur + msg * a;
    atomicAdd(&out[t * DIM + j], val);
}

extern "C" void kernel_launch(void* const* d_in, const int* in_sizes, int n_in,
                              void* d_out, int out_size, void* d_ws, size_t ws_size,
                              hipStream_t stream) {
    const float* node_feat = (const float*)d_in[0];
    const float* ttr       = (const float*)d_in[1];
    const float* tre       = (const float*)d_in[2];
    const float* weight    = (const float*)d_in[3];
    const float* w_comp    = (const float*)d_in[4];
    const float* slw       = (const float*)d_in[5];
    const float* Aw        = (const float*)d_in[6];
    const float* Ab        = (const float*)d_in[7];
    const float* Bw        = (const float*)d_in[8];
    const float* Bb        = (const float*)d_in[9];
    const int*  total_edge = (const int*)d_in[10];   // [2,E]
    const int*  rel        = (const int*)d_in[11];   // [E]
    const int*  edge0 = total_edge;
    const int*  edge1 = total_edge + N_EDGES;

    float* rel_w = (float*)d_ws;
    float* out   = (float*)d_out;

    // out is poisoned 0xAA each call — zero it, then scatter-add into it
    hipMemsetAsync(out, 0, OUT_ELEMS * sizeof(float), stream);

    relw_kernel<<<N_REL, 256, 0, stream>>>(weight, w_comp, rel_w);

    edge_kernel<<<(N_EDGES + E_PER_BLOCK - 1) / E_PER_BLOCK, 256, 0, stream>>>(
        node_feat, ttr, tre, slw, Aw, Ab, Bw, Bb,
        edge0, edge1, rel, rel_w, out);
}

// Round 3
// 313.050 us; speedup vs baseline: 1.4975x; 1.4975x over previous
//
#include <hip/hip_runtime.h>

// Problem constants (from reference)
#define N_NODES 12500
#define N_EDGES 200000
#define DIM 32          // IN == OUT == ATTN == 32
#define N_REL 200
#define N_BASES 50
#define E_PER_BLOCK 8

#define OUT_ELEMS   (N_NODES * DIM)
#define ZERO_BLOCKS ((OUT_ELEMS + 1023) / 1024)   // 391 blocks x 1024 floats

// sA leading-dim pad: stride 33 floats kills the 64-way staging-write
// bank conflict (write bank (kk+jj)%32 instead of constant jj).
#define SA_STRIDE 33

// Kernel 1 (fused prep): blocks [0,200) compute rel_w; blocks [200,591) zero out.
__global__ __launch_bounds__(256) void prep_kernel(
    const float* __restrict__ weight,   // [NB, IN, OUT] = [50,32,32]
    const float* __restrict__ w_comp,   // [R, NB] = [200,50]
    float* __restrict__ rel_w,          // [R, 1024]
    float* __restrict__ out)            // [N,32] -> zeroed
{
    if (blockIdx.x < N_REL) {
        __shared__ float wc[N_BASES];
        int r = blockIdx.x;
        int tid = threadIdx.x;
        if (tid < N_BASES) wc[tid] = w_comp[r * N_BASES + tid];
        __syncthreads();
        for (int t = 0; t < 4; t++) {
            int idx = tid + t * 256;          // [0,1024)
            float sum = 0.f;
            #pragma unroll 10
            for (int b = 0; b < N_BASES; b++)
                sum = fmaf(wc[b], weight[b * 1024 + idx], sum);
            rel_w[r * 1024 + idx] = sum;
        }
    } else {
        int base = (blockIdx.x - N_REL) * 1024 + threadIdx.x * 4;
        if (base + 3 < OUT_ELEMS) {
            *(float4*)(out + base) = make_float4(0.f, 0.f, 0.f, 0.f);
        } else {
            for (int k = 0; k < 4; k++)
                if (base + k < OUT_ELEMS) out[base + k] = 0.f;
        }
    }
}

// Kernel 2: per-edge transform + attention gate + scatter-add into fp32 out.
// 32 lanes per edge (lane j = output dim), 8 edges per 256-thread block.
__global__ __launch_bounds__(256) void edge_kernel(
    const float* __restrict__ node_feat,  // [N,32]
    const float* __restrict__ ttr,        // total_target_relation [E,32]
    const float* __restrict__ tre,        // total_relation_embed  [E,32]
    const float* __restrict__ slw,        // self_loop_weight [32,32]
    const float* __restrict__ Aw,         // [32,128]
    const float* __restrict__ Ab,         // [32]
    const float* __restrict__ Bw,         // [1,32]
    const float* __restrict__ Bb,         // [1]
    const int*  __restrict__ edge0,       // sources [E]
    const int*  __restrict__ edge1,       // targets [E]
    const int*  __restrict__ rel,         // [E]
    const float* __restrict__ rel_w,      // [R,1024] fp32
    float* __restrict__ out)              // [N,32] fp32 (pre-zeroed)
{
    // sA[k*33+j] = Aw[j,k]; pad-33 => writes hit bank (kk+jj)%32 (conflict-
    // free), reads hit banks (k+j)%32, all 32 distinct across lanes.
    __shared__ float sA[128 * SA_STRIDE];   // 16.5 KB
    __shared__ float sS[32 * 32];           // 4 KB, sS[i*32+j] = slw[i,j]
    __shared__ float sAb[32];
    __shared__ float sBw[32];

    int tid = threadIdx.x;
    for (int x = tid; x < 128 * 32; x += 256) {
        int jj = x >> 7;      // row of Aw (output dim j)
        int kk = x & 127;     // col of Aw (input dim k)
        sA[kk * SA_STRIDE + jj] = Aw[x];
    }
    for (int x = tid; x < 1024; x += 256) sS[x] = slw[x];
    if (tid < 32) { sAb[tid] = Ab[tid]; sBw[tid] = Bw[tid]; }
    __syncthreads();

    float Bb0 = Bb[0];

    int eid = blockIdx.x * E_PER_BLOCK + (tid >> 5);
    int j = tid & 31;
    if (eid >= N_EDGES) return;

    // clamped for safety: OOB would NaN-poison the scatter-add
    int s = edge0[eid]; s = s < 0 ? 0 : (s >= N_NODES ? N_NODES - 1 : s);
    int t = edge1[eid]; t = t < 0 ? 0 : (t >= N_NODES ? N_NODES - 1 : t);
    int r = rel[eid];   r = r < 0 ? 0 : (r >= N_REL   ? N_REL   - 1 : r);

    float srcj = node_feat[s * DIM + j];
    float tgtj = node_feat[t * DIM + j];
    float rej  = tre[eid * DIM + j];
    float trj  = ttr[eid * DIM + j];

    const float* __restrict__ rw = rel_w + r * 1024;

    float msg = 0.f, cur = 0.f;
    float h = sAb[j];
    #pragma unroll 8
    for (int i = 0; i < 32; i++) {
        float si = __shfl(srcj, i, 32);
        float ti = __shfl(tgtj, i, 32);
        float ri = __shfl(rej,  i, 32);
        float qi = __shfl(trj,  i, 32);
        msg = fmaf(si, rw[i * 32 + j], msg);
        cur = fmaf(ti, sS[i * 32 + j], cur);
        h = fmaf(sA[( 0 + i) * SA_STRIDE + j], si, h);
        h = fmaf(sA[(32 + i) * SA_STRIDE + j], ti, h);
        h = fmaf(sA[(64 + i) * SA_STRIDE + j], ri, h);
        h = fmaf(sA[(96 + i) * SA_STRIDE + j], qi, h);
    }
    h = fmaxf(h, 0.f);                 // relu
    float p = h * sBw[j];
    #pragma unroll
    for (int m = 16; m > 0; m >>= 1) p += __shfl_xor(p, m, 32);
    float a = 1.f / (1.f + __expf(-(p + Bb0)));   // sigmoid

    float val = cur + msg * a;
    atomicAdd(&out[t * DIM + j], val);
}

extern "C" void kernel_launch(void* const* d_in, const int* in_sizes, int n_in,
                              void* d_out, int out_size, void* d_ws, size_t ws_size,
                              hipStream_t stream) {
    const float* node_feat = (const float*)d_in[0];
    const float* ttr       = (const float*)d_in[1];
    const float* tre       = (const float*)d_in[2];
    const float* weight    = (const float*)d_in[3];
    const float* w_comp    = (const float*)d_in[4];
    const float* slw       = (const float*)d_in[5];
    const float* Aw        = (const float*)d_in[6];
    const float* Ab        = (const float*)d_in[7];
    const float* Bw        = (const float*)d_in[8];
    const float* Bb        = (const float*)d_in[9];
    const int*  total_edge = (const int*)d_in[10];   // [2,E]
    const int*  rel        = (const int*)d_in[11];   // [E]
    const int*  edge0 = total_edge;
    const int*  edge1 = total_edge + N_EDGES;

    float* rel_w = (float*)d_ws;
    float* out   = (float*)d_out;

    prep_kernel<<<N_REL + ZERO_BLOCKS, 256, 0, stream>>>(weight, w_comp, rel_w, out);

    edge_kernel<<<(N_EDGES + E_PER_BLOCK - 1) / E_PER_BLOCK, 256, 0, stream>>>(
        node_feat, ttr, tre, slw, Aw, Ab, Bw, Bb,
        edge0, edge1, rel, rel_w, out);
}

// Round 4
// 169.726 us; speedup vs baseline: 2.7621x; 1.8444x over previous
//
#include <hip/hip_runtime.h>

// Problem constants (from reference)
#define N_NODES 12500
#define N_EDGES 200000
#define DIM 32          // IN == OUT == ATTN == 32
#define N_REL 200
#define N_BASES 50

#define OUT_ELEMS   (N_NODES * DIM)
#define ZERO_BLOCKS ((OUT_ELEMS + 1023) / 1024)   // 391

// ws layout (bytes):
//   [0, 819200)            float rel_w[200][32][32]
//   [819200, +8192)        bf16  aw_bf[32][128]      (= A_w, row-major)
//   [827392, +2048)        bf16  slwT_bf[32][32]     (= slw transposed [j][i])
#define AWBF_OFF  (N_REL * 1024 * 4)
#define SLWT_OFF  (AWBF_OFF + 32 * 128 * 2)

typedef __attribute__((ext_vector_type(8))) short short8;   // 8 bf16 (4 VGPRs)
typedef __attribute__((ext_vector_type(4))) float f32x4;    // MFMA acc

__device__ __forceinline__ unsigned short f2bf(float x) {
    union { float f; unsigned u; } v; v.f = x;
    unsigned r = (v.u + 0x7FFFu + ((v.u >> 16) & 1u)) >> 16;
    return (unsigned short)r;
}

__device__ __forceinline__ short8 cvt8(float4 a, float4 b) {
    short8 r;
    r[0] = (short)f2bf(a.x); r[1] = (short)f2bf(a.y);
    r[2] = (short)f2bf(a.z); r[3] = (short)f2bf(a.w);
    r[4] = (short)f2bf(b.x); r[5] = (short)f2bf(b.y);
    r[6] = (short)f2bf(b.z); r[7] = (short)f2bf(b.w);
    return r;
}

#define MFMA(A, B, C) __builtin_amdgcn_mfma_f32_16x16x32_bf16(A, B, C, 0, 0, 0)

// Prep: blocks [0,200) rel_w; [200,591) zero out; block 591 converts Aw/slwT.
__global__ __launch_bounds__(256) void prep_kernel(
    const float* __restrict__ weight,   // [50,32,32]
    const float* __restrict__ w_comp,   // [200,50]
    const float* __restrict__ Aw,       // [32,128]
    const float* __restrict__ slw,      // [32,32]
    float* __restrict__ rel_w,
    unsigned short* __restrict__ aw_bf,
    unsigned short* __restrict__ slwT_bf,
    float* __restrict__ out)
{
    int b = blockIdx.x, tid = threadIdx.x;
    if (b < N_REL) {
        __shared__ float wc[N_BASES];
        if (tid < N_BASES) wc[tid] = w_comp[b * N_BASES + tid];
        __syncthreads();
        for (int t = 0; t < 4; t++) {
            int idx = tid + t * 256;
            float sum = 0.f;
            #pragma unroll 10
            for (int bb = 0; bb < N_BASES; bb++)
                sum = fmaf(wc[bb], weight[bb * 1024 + idx], sum);
            rel_w[b * 1024 + idx] = sum;
        }
    } else if (b < N_REL + ZERO_BLOCKS) {
        int base = (b - N_REL) * 1024 + tid * 4;
        if (base + 3 < OUT_ELEMS)
            *(float4*)(out + base) = make_float4(0.f, 0.f, 0.f, 0.f);
        else
            for (int k = 0; k < 4; k++)
                if (base + k < OUT_ELEMS) out[base + k] = 0.f;
    } else {
        for (int x = tid; x < 32 * 128; x += 256) aw_bf[x] = f2bf(Aw[x]);
        for (int x = tid; x < 32 * 32; x += 256) {
            int i = x >> 5, j = x & 31;          // slw[i][j]
            slwT_bf[j * 32 + i] = f2bf(slw[x]);
        }
    }
}

// Edge kernel: one wave = 16 edges. h & cur via MFMA (weights in register
// fragments, zero DS); msg via VALU with bpermute src broadcasts + fp32
// rel_w rows from L2. LDS only for msg layout swap into MFMA C/D layout.
__global__ __launch_bounds__(256) void edge_kernel(
    const float* __restrict__ node_feat,  // [N,32]
    const float* __restrict__ ttr,        // [E,32]
    const float* __restrict__ tre,        // [E,32]
    const float* __restrict__ Ab,         // [32]
    const float* __restrict__ Bw,         // [1,32]
    const float* __restrict__ Bb,         // [1]
    const int*  __restrict__ edge0,       // [E]
    const int*  __restrict__ edge1,       // [E]
    const int*  __restrict__ rel,         // [E]
    const float* __restrict__ rel_w,      // [200][32][32] fp32
    const unsigned short* __restrict__ aw_bf,   // [32][128] bf16
    const unsigned short* __restrict__ slwT_bf, // [32][32]  bf16 (T)
    float* __restrict__ out)              // [N,32] fp32 (pre-zeroed)
{
    __shared__ float msgL[4 * 16 * 36];   // per-wave 16x36 slice (9.2 KB)

    int tid  = threadIdx.x;
    int wave = tid >> 6;
    int lane = tid & 63;
    int m = lane & 15;          // edge row (A-frag) / out col n (B,C/D frag)
    int q = lane >> 4;          // quad: k-range / row-group
    int base = blockIdx.x * 64 + wave * 16;   // 3125*64 == 200000 exactly

    // lanes<16 load edge indices; everyone else gets them via shfl
    int s_ld = 0, t_ld = 0, r_ld = 0;
    if (lane < 16) {
        int eid = base + lane;
        int s = edge0[eid]; s_ld = s < 0 ? 0 : (s >= N_NODES ? N_NODES - 1 : s);
        int t = edge1[eid]; t_ld = t < 0 ? 0 : (t >= N_NODES ? N_NODES - 1 : t);
        int r = rel[eid];   r_ld = r < 0 ? 0 : (r >= N_REL   ? N_REL   - 1 : r);
    }
    int s_m = __shfl(s_ld, m, 64);
    int t_m = __shfl(t_ld, m, 64);
    int eid_m = base + m;

    // ---- gather A-operand data (lane holds edge m, k = 8q..8q+7) ----
    const float* sp = node_feat + s_m * DIM + q * 8;
    float4 sv0 = *(const float4*)sp, sv1 = *(const float4*)(sp + 4);
    const float* tp = node_feat + t_m * DIM + q * 8;
    float4 tv0 = *(const float4*)tp, tv1 = *(const float4*)(tp + 4);
    const float* rp = tre + eid_m * DIM + q * 8;
    float4 rv0 = *(const float4*)rp, rv1 = *(const float4*)(rp + 4);
    const float* qp = ttr + eid_m * DIM + q * 8;
    float4 qv0 = *(const float4*)qp, qv1 = *(const float4*)(qp + 4);

    short8 fsrc = cvt8(sv0, sv1);
    short8 ftgt = cvt8(tv0, tv1);
    short8 fre  = cvt8(rv0, rv1);
    short8 ftr  = cvt8(qv0, qv1);

    // ---- B-operand fragments (lane: n = m, k = 8q..8q+7) ----
    // aw_bf[j][k]: B[k][n=j] for h; slwT_bf[j][i]: B[i][j] for cur
    short8 bA[4][2], bS[2];
    #pragma unroll
    for (int hh = 0; hh < 2; hh++) {
        #pragma unroll
        for (int c = 0; c < 4; c++)
            bA[c][hh] = *(const short8*)(aw_bf + (16 * hh + m) * 128 + 32 * c + 8 * q);
        bS[hh] = *(const short8*)(slwT_bf + (16 * hh + m) * 32 + 8 * q);
    }

    // ---- MFMAs: h = Ecat @ Aw^T + Ab ; cur = tgt @ slw ----
    float ab0 = Ab[m], ab1 = Ab[16 + m];
    f32x4 hacc0 = {ab0, ab0, ab0, ab0};
    f32x4 hacc1 = {ab1, ab1, ab1, ab1};
    f32x4 cacc0 = {0.f, 0.f, 0.f, 0.f};
    f32x4 cacc1 = {0.f, 0.f, 0.f, 0.f};

    hacc0 = MFMA(fsrc, bA[0][0], hacc0);  hacc1 = MFMA(fsrc, bA[0][1], hacc1);
    hacc0 = MFMA(ftgt, bA[1][0], hacc0);  hacc1 = MFMA(ftgt, bA[1][1], hacc1);
    hacc0 = MFMA(fre,  bA[2][0], hacc0);  hacc1 = MFMA(fre,  bA[2][1], hacc1);
    hacc0 = MFMA(ftr,  bA[3][0], hacc0);  hacc1 = MFMA(ftr,  bA[3][1], hacc1);
    cacc0 = MFMA(ftgt, bS[0], cacc0);     cacc1 = MFMA(ftgt, bS[1], cacc1);

    // ---- msg (fp32 VALU): lane = (edge e_loc, col-chunk cq*8..+7) ----
    int e_loc = lane >> 2;
    int cq    = lane & 3;
    int r_e = __shfl(r_ld, e_loc, 64);
    const float* rw = rel_w + r_e * 1024 + cq * 8;
    float sf[8] = {sv0.x, sv0.y, sv0.z, sv0.w, sv1.x, sv1.y, sv1.z, sv1.w};
    float msg[8] = {0.f, 0.f, 0.f, 0.f, 0.f, 0.f, 0.f, 0.f};
    #pragma unroll
    for (int k = 0; k < 32; k++) {
        float s_k = __shfl(sf[k & 7], e_loc + 16 * (k >> 3), 64);
        float4 w0 = *(const float4*)(rw + k * 32);
        float4 w1 = *(const float4*)(rw + k * 32 + 4);
        msg[0] = fmaf(s_k, w0.x, msg[0]); msg[1] = fmaf(s_k, w0.y, msg[1]);
        msg[2] = fmaf(s_k, w0.z, msg[2]); msg[3] = fmaf(s_k, w0.w, msg[3]);
        msg[4] = fmaf(s_k, w1.x, msg[4]); msg[5] = fmaf(s_k, w1.y, msg[5]);
        msg[6] = fmaf(s_k, w1.z, msg[6]); msg[7] = fmaf(s_k, w1.w, msg[7]);
    }

    // relayout msg -> C/D layout via LDS (stride 36: 16B-aligned, low-conflict)
    float* ml = msgL + wave * (16 * 36);
    *(float4*)(ml + e_loc * 36 + cq * 8)     = make_float4(msg[0], msg[1], msg[2], msg[3]);
    *(float4*)(ml + e_loc * 36 + cq * 8 + 4) = make_float4(msg[4], msg[5], msg[6], msg[7]);
    __syncthreads();

    // ---- epilogue: gate a = sigmoid(relu(h)@Bw + Bb), combine, scatter ----
    float bw0 = Bw[m], bw1 = Bw[16 + m], Bb0 = Bb[0];
    float av[4];
    #pragma unroll
    for (int v = 0; v < 4; v++) {
        float p = fmaxf(hacc0[v], 0.f) * bw0 + fmaxf(hacc1[v], 0.f) * bw1;
        p += __shfl_xor(p, 1, 16);
        p += __shfl_xor(p, 2, 16);
        p += __shfl_xor(p, 4, 16);
        p += __shfl_xor(p, 8, 16);
        av[v] = 1.f / (1.f + __expf(-(p + Bb0)));
    }
    #pragma unroll
    for (int v = 0; v < 4; v++) {
        int row = 4 * q + v;
        int tv = __shfl(t_ld, row, 64);
        float m0 = ml[row * 36 + m];
        float m1 = ml[row * 36 + 16 + m];
        atomicAdd(&out[tv * DIM + m],      cacc0[v] + m0 * av[v]);
        atomicAdd(&out[tv * DIM + 16 + m], cacc1[v] + m1 * av[v]);
    }
}

extern "C" void kernel_launch(void* const* d_in, const int* in_sizes, int n_in,
                              void* d_out, int out_size, void* d_ws, size_t ws_size,
                              hipStream_t stream) {
    const float* node_feat = (const float*)d_in[0];
    const float* ttr       = (const float*)d_in[1];
    const float* tre       = (const float*)d_in[2];
    const float* weight    = (const float*)d_in[3];
    const float* w_comp    = (const float*)d_in[4];
    const float* slw       = (const float*)d_in[5];
    const float* Aw        = (const float*)d_in[6];
    const float* Ab        = (const float*)d_in[7];
    const float* Bw        = (const float*)d_in[8];
    const float* Bb        = (const float*)d_in[9];
    const int*  total_edge = (const int*)d_in[10];
    const int*  rel        = (const int*)d_in[11];
    const int*  edge0 = total_edge;
    const int*  edge1 = total_edge + N_EDGES;

    float* rel_w = (float*)d_ws;
    unsigned short* aw_bf   = (unsigned short*)((char*)d_ws + AWBF_OFF);
    unsigned short* slwT_bf = (unsigned short*)((char*)d_ws + SLWT_OFF);
    float* out = (float*)d_out;

    prep_kernel<<<N_REL + ZERO_BLOCKS + 1, 256, 0, stream>>>(
        weight, w_comp, Aw, slw, rel_w, aw_bf, slwT_bf, out);

    edge_kernel<<<N_EDGES / 64, 256, 0, stream>>>(
        node_feat, ttr, tre, Ab, Bw, Bb,
        edge0, edge1, rel, rel_w, aw_bf, slwT_bf, out);
}

// Round 5
// 152.768 us; speedup vs baseline: 3.0687x; 1.1110x over previous
//
#include <hip/hip_runtime.h>

// Problem constants (from reference)
#define N_NODES 12500
#define N_EDGES 200000
#define DIM 32          // IN == OUT == ATTN == 32
#define N_REL 200
#define N_BASES 50

#define OUT_ELEMS   (N_NODES * DIM)
#define ZERO_BLOCKS ((OUT_ELEMS + 1023) / 1024)   // 391

// ws layout (bytes):
//   [0, 409600)         bf16 relw_bf[200][32][32]
//   [409600, +8192)     bf16 aw_bf[32][128]      (= A_w, row-major)
//   [417792, +2048)     bf16 slwT_bf[32][32]     (= slw transposed [j][i])
#define AWBF_OFF  (N_REL * 1024 * 2)
#define SLWT_OFF  (AWBF_OFF + 32 * 128 * 2)

typedef __attribute__((ext_vector_type(8))) short short8;   // 8 bf16 (4 VGPRs)
typedef __attribute__((ext_vector_type(4))) float f32x4;    // MFMA acc
typedef __attribute__((ext_vector_type(4))) unsigned short us4;

__device__ __forceinline__ unsigned short f2bf(float x) {
    union { float f; unsigned u; } v; v.f = x;
    unsigned r = (v.u + 0x7FFFu + ((v.u >> 16) & 1u)) >> 16;
    return (unsigned short)r;
}

__device__ __forceinline__ short8 cvt8(float4 a, float4 b) {
    short8 r;
    r[0] = (short)f2bf(a.x); r[1] = (short)f2bf(a.y);
    r[2] = (short)f2bf(a.z); r[3] = (short)f2bf(a.w);
    r[4] = (short)f2bf(b.x); r[5] = (short)f2bf(b.y);
    r[6] = (short)f2bf(b.z); r[7] = (short)f2bf(b.w);
    return r;
}

#define MFMA(A, B, C) __builtin_amdgcn_mfma_f32_16x16x32_bf16(A, B, C, 0, 0, 0)

// Prep: blocks [0,200) rel_w (bf16 out, float4-coalesced weight loads);
//       [200,591) zero out; block 591 converts Aw/slwT.
__global__ __launch_bounds__(256) void prep_kernel(
    const float* __restrict__ weight,   // [50,32,32]
    const float* __restrict__ w_comp,   // [200,50]
    const float* __restrict__ Aw,       // [32,128]
    const float* __restrict__ slw,      // [32,32]
    unsigned short* __restrict__ relw_bf,
    unsigned short* __restrict__ aw_bf,
    unsigned short* __restrict__ slwT_bf,
    float* __restrict__ out)
{
    int b = blockIdx.x, tid = threadIdx.x;
    if (b < N_REL) {
        __shared__ float wc[N_BASES];
        if (tid < N_BASES) wc[tid] = w_comp[b * N_BASES + tid];
        __syncthreads();
        // thread -> 4 consecutive outputs; weight loads are float4,
        // wave-contiguous 1KB per inst (R4 post-mortem: the scalar
        // stride-4KB version was ~65-90us latency-bound at 1 block/CU)
        const float* wp = weight + tid * 4;
        float4 acc = make_float4(0.f, 0.f, 0.f, 0.f);
        #pragma unroll 10
        for (int bb = 0; bb < N_BASES; bb++) {
            float4 w = *(const float4*)(wp + bb * 1024);
            float c = wc[bb];
            acc.x = fmaf(c, w.x, acc.x); acc.y = fmaf(c, w.y, acc.y);
            acc.z = fmaf(c, w.z, acc.z); acc.w = fmaf(c, w.w, acc.w);
        }
        us4 o;
        o[0] = f2bf(acc.x); o[1] = f2bf(acc.y);
        o[2] = f2bf(acc.z); o[3] = f2bf(acc.w);
        *(us4*)(relw_bf + b * 1024 + tid * 4) = o;
    } else if (b < N_REL + ZERO_BLOCKS) {
        int base = (b - N_REL) * 1024 + tid * 4;
        if (base + 3 < OUT_ELEMS)
            *(float4*)(out + base) = make_float4(0.f, 0.f, 0.f, 0.f);
        else
            for (int k = 0; k < 4; k++)
                if (base + k < OUT_ELEMS) out[base + k] = 0.f;
    } else {
        for (int x = tid; x < 32 * 128; x += 256) aw_bf[x] = f2bf(Aw[x]);
        for (int x = tid; x < 32 * 32; x += 256) {
            int i = x >> 5, j = x & 31;          // slw[i][j]
            slwT_bf[j * 32 + i] = f2bf(slw[x]);
        }
    }
}

// Edge kernel: one wave = 16 edges. h & cur via MFMA (weights in register
// fragments); msg via VALU with shfl src broadcasts + bf16 rel_w rows (L2).
// LDS only for per-wave msg relayout into MFMA C/D layout (no barrier:
// each wave touches only its own slice).
__global__ __launch_bounds__(256) void edge_kernel(
    const float* __restrict__ node_feat,  // [N,32]
    const float* __restrict__ ttr,        // [E,32]
    const float* __restrict__ tre,        // [E,32]
    const float* __restrict__ Ab,         // [32]
    const float* __restrict__ Bw,         // [1,32]
    const float* __restrict__ Bb,         // [1]
    const int*  __restrict__ edge0,       // [E]
    const int*  __restrict__ edge1,       // [E]
    const int*  __restrict__ rel,         // [E]
    const unsigned short* __restrict__ relw_bf, // [200][32][32] bf16
    const unsigned short* __restrict__ aw_bf,   // [32][128] bf16
    const unsigned short* __restrict__ slwT_bf, // [32][32]  bf16 (T)
    float* __restrict__ out)              // [N,32] fp32 (pre-zeroed)
{
    __shared__ float msgL[4 * 16 * 36];   // per-wave 16x36 slice (9.2 KB)

    int tid  = threadIdx.x;
    int wave = tid >> 6;
    int lane = tid & 63;
    int m = lane & 15;          // edge row (A-frag) / out col n (B,C/D frag)
    int q = lane >> 4;          // quad: k-range / row-group
    int base = blockIdx.x * 64 + wave * 16;   // 3125*64 == 200000 exactly

    // lanes<16 load edge indices; everyone else gets them via shfl
    int s_ld = 0, t_ld = 0, r_ld = 0;
    if (lane < 16) {
        int eid = base + lane;
        int s = edge0[eid]; s_ld = s < 0 ? 0 : (s >= N_NODES ? N_NODES - 1 : s);
        int t = edge1[eid]; t_ld = t < 0 ? 0 : (t >= N_NODES ? N_NODES - 1 : t);
        int r = rel[eid];   r_ld = r < 0 ? 0 : (r >= N_REL   ? N_REL   - 1 : r);
    }
    int s_m = __shfl(s_ld, m, 64);
    int t_m = __shfl(t_ld, m, 64);
    int eid_m = base + m;

    // ---- gather A-operand data (lane holds edge m, k = 8q..8q+7) ----
    const float* sp = node_feat + s_m * DIM + q * 8;
    float4 sv0 = *(const float4*)sp, sv1 = *(const float4*)(sp + 4);
    const float* tp = node_feat + t_m * DIM + q * 8;
    float4 tv0 = *(const float4*)tp, tv1 = *(const float4*)(tp + 4);
    const float* rp = tre + eid_m * DIM + q * 8;
    float4 rv0 = *(const float4*)rp, rv1 = *(const float4*)(rp + 4);
    const float* qp = ttr + eid_m * DIM + q * 8;
    float4 qv0 = *(const float4*)qp, qv1 = *(const float4*)(qp + 4);

    short8 fsrc = cvt8(sv0, sv1);
    short8 ftgt = cvt8(tv0, tv1);
    short8 fre  = cvt8(rv0, rv1);
    short8 ftr  = cvt8(qv0, qv1);

    // ---- B-operand fragments (lane: n = m, k = 8q..8q+7) ----
    short8 bA[4][2], bS[2];
    #pragma unroll
    for (int hh = 0; hh < 2; hh++) {
        #pragma unroll
        for (int c = 0; c < 4; c++)
            bA[c][hh] = *(const short8*)(aw_bf + (16 * hh + m) * 128 + 32 * c + 8 * q);
        bS[hh] = *(const short8*)(slwT_bf + (16 * hh + m) * 32 + 8 * q);
    }

    // ---- MFMAs: h = Ecat @ Aw^T + Ab ; cur = tgt @ slw ----
    float ab0 = Ab[m], ab1 = Ab[16 + m];
    f32x4 hacc0 = {ab0, ab0, ab0, ab0};
    f32x4 hacc1 = {ab1, ab1, ab1, ab1};
    f32x4 cacc0 = {0.f, 0.f, 0.f, 0.f};
    f32x4 cacc1 = {0.f, 0.f, 0.f, 0.f};

    hacc0 = MFMA(fsrc, bA[0][0], hacc0);  hacc1 = MFMA(fsrc, bA[0][1], hacc1);
    hacc0 = MFMA(ftgt, bA[1][0], hacc0);  hacc1 = MFMA(ftgt, bA[1][1], hacc1);
    hacc0 = MFMA(fre,  bA[2][0], hacc0);  hacc1 = MFMA(fre,  bA[2][1], hacc1);
    hacc0 = MFMA(ftr,  bA[3][0], hacc0);  hacc1 = MFMA(ftr,  bA[3][1], hacc1);
    cacc0 = MFMA(ftgt, bS[0], cacc0);     cacc1 = MFMA(ftgt, bS[1], cacc1);

    // ---- msg (fp32 acc, bf16 weights): lane = (edge e_loc, col-chunk cq) ----
    int e_loc = lane >> 2;
    int cq    = lane & 3;
    int r_e = __shfl(r_ld, e_loc, 64);
    const unsigned short* rwb = relw_bf + r_e * 1024 + cq * 8;
    float sf[8] = {sv0.x, sv0.y, sv0.z, sv0.w, sv1.x, sv1.y, sv1.z, sv1.w};
    float msg[8] = {0.f, 0.f, 0.f, 0.f, 0.f, 0.f, 0.f, 0.f};
    #pragma unroll
    for (int k = 0; k < 32; k++) {
        float s_k = __shfl(sf[k & 7], e_loc + 16 * (k >> 3), 64);
        union { short8 s; unsigned u[4]; } W;
        W.s = *(const short8*)(rwb + k * 32);
        #pragma unroll
        for (int p = 0; p < 4; p++) {
            float lo = __uint_as_float(W.u[p] << 16);
            float hi = __uint_as_float(W.u[p] & 0xffff0000u);
            msg[2 * p]     = fmaf(s_k, lo, msg[2 * p]);
            msg[2 * p + 1] = fmaf(s_k, hi, msg[2 * p + 1]);
        }
    }

    // relayout msg -> C/D layout via LDS (per-wave slice; compiler inserts
    // the lgkmcnt wait for the same-wave write->read dependency)
    float* ml = msgL + wave * (16 * 36);
    *(float4*)(ml + e_loc * 36 + cq * 8)     = make_float4(msg[0], msg[1], msg[2], msg[3]);
    *(float4*)(ml + e_loc * 36 + cq * 8 + 4) = make_float4(msg[4], msg[5], msg[6], msg[7]);

    // ---- epilogue: gate a = sigmoid(relu(h)@Bw + Bb), combine, scatter ----
    float bw0 = Bw[m], bw1 = Bw[16 + m], Bb0 = Bb[0];
    float av[4];
    #pragma unroll
    for (int v = 0; v < 4; v++) {
        float p = fmaxf(hacc0[v], 0.f) * bw0 + fmaxf(hacc1[v], 0.f) * bw1;
        p += __shfl_xor(p, 1, 16);
        p += __shfl_xor(p, 2, 16);
        p += __shfl_xor(p, 4, 16);
        p += __shfl_xor(p, 8, 16);
        av[v] = 1.f / (1.f + __expf(-(p + Bb0)));
    }
    #pragma unroll
    for (int v = 0; v < 4; v++) {
        int row = 4 * q + v;
        int tv = __shfl(t_ld, row, 64);
        float m0 = ml[row * 36 + m];
        float m1 = ml[row * 36 + 16 + m];
        atomicAdd(&out[tv * DIM + m],      cacc0[v] + m0 * av[v]);
        atomicAdd(&out[tv * DIM + 16 + m], cacc1[v] + m1 * av[v]);
    }
}

extern "C" void kernel_launch(void* const* d_in, const int* in_sizes, int n_in,
                              void* d_out, int out_size, void* d_ws, size_t ws_size,
                              hipStream_t stream) {
    const float* node_feat = (const float*)d_in[0];
    const float* ttr       = (const float*)d_in[1];
    const float* tre       = (const float*)d_in[2];
    const float* weight    = (const float*)d_in[3];
    const float* w_comp    = (const float*)d_in[4];
    const float* slw       = (const float*)d_in[5];
    const float* Aw        = (const float*)d_in[6];
    const float* Ab        = (const float*)d_in[7];
    const float* Bw        = (const float*)d_in[8];
    const float* Bb        = (const float*)d_in[9];
    const int*  total_edge = (const int*)d_in[10];
    const int*  rel        = (const int*)d_in[11];
    const int*  edge0 = total_edge;
    const int*  edge1 = total_edge + N_EDGES;

    unsigned short* relw_bf = (unsigned short*)d_ws;
    unsigned short* aw_bf   = (unsigned short*)((char*)d_ws + AWBF_OFF);
    unsigned short* slwT_bf = (unsigned short*)((char*)d_ws + SLWT_OFF);
    float* out = (float*)d_out;

    prep_kernel<<<N_REL + ZERO_BLOCKS + 1, 256, 0, stream>>>(
        weight, w_comp, Aw, slw, relw_bf, aw_bf, slwT_bf, out);

    edge_kernel<<<N_EDGES / 64, 256, 0, stream>>>(
        node_feat, ttr, tre, Ab, Bw, Bb,
        edge0, edge1, rel, relw_bf, aw_bf, slwT_bf, out);
}